// Round 3
// baseline (676.589 us; speedup 1.0000x reference)
//
#include <hip/hip_runtime.h>
#include <stdint.h>
#include <stddef.h>

// ============================================================================
// y = x @ W^T + bias via bf16 MFMA, 256x256 tile, 8-wave, 8-phase pipelined
// schedule with FINE-GRAINED read spreading (learn_hip m201/m196: the lever
// is ds_read ∥ MFMA interleave, not the phase split itself).
//
// ROUND-3 CHANGE: register loads are software-pipelined ONE PHASE AHEAD and
// spread 4/8/8/4 per phase, so each phase's MFMA (consuming phase p-1 reads)
// overlaps phase p's ds_reads. R2 bunched 16 reads in P1/P5 with same-phase
// consumption -> LDS time (4608 cy/iter) ADDED to MFMA time (4966 cy/iter);
// model total 255us == measured 257us. Spread+pipelined -> per-iter ~
// max(LDS,MFMA) ~= 6500 cy -> ~180us predicted.
//
// SCHEDULE LEDGER (re-derived; keep in sync):
//   Slots: buf0: s0=B.lo s1=B.hi s2=A.lo s3=A.hi; buf1: s4..s7 same order.
//   Wave owns 128(M)x64(N): wrow=wave>>2 -> A slot (s2/s3 | s6/s7);
//   wcol=wave&3 -> B slot (wcol>>1) + 64-col half (bro).
//   Iteration I computes tile 2I (buf0, P1-P4) and 2I+1 (buf1, P5-P8).
//   Per phase: [ds_reads for p+1][STAGE 1 half-tile][BAR][16 MFMA]
//              [vmcnt(N guards p+1 reads)][BAR]
//   Reads:  P1: bfr23(2I)    <- s0/s1   P5: bfr23(2I+1) <- s4/s5
//           P2: afB(2I)      <- s2/s3   P6: afB(2I+1)   <- s6/s7
//           P3: afA(2I+1)    <- s6/s7   P7: afA(2I+2)   <- s2/s3
//           P4: bfr01(2I+1)  <- s4/s5   P8: bfr01(2I+2) <- s0/s1
//   MFMA:   P1: Q(0,0)=afA*b01  P2: Q(0,1)=afA*b23
//           P3: Q(1,0)=afB*b01  P4: Q(1,1)=afB*b23   (P5-P8 mirror)
//   Single-buffered frags, no WAR: each reload is >=1 phase after the old
//   value's last MFMA use (afA used P1,P2 reload P3; afB used P3,P4 reload
//   P6... wait P2; b01 used P1,P3 reload P4; b23 used P2,P4 reload P5; all
//   verified, mirror likewise).
//   Stage ring: P1:s7(A.hi,2I+1) P2:s4(B.lo,2I+1) P3:s0(B.lo,2I+2)
//               P4:s2(A.lo,2I+2) P5:s3(A.hi,2I+2) P6:s1(B.hi,2I+2)
//               P7:s5(B.hi,2I+3) P8:s6(A.lo,2I+3)
//   Overwrite gaps (last read -> restage): s7:3 s4:5 s0:2 s2:2 s3:3 s1:5
//   s5:2 s6:2 -- all >=2 phases (~1400cy) >> LDS-FIFO backlog (<800cy): no
//   lgkm guards needed.
//   vmcnt guards (placed pre-closing-barrier at p, guarding reads at p+1;
//   cross-wave proof: X's vmcnt -> X enters barrier -> Y reads. N<=2(m-1),
//   m = min stage->read margin of p+1's slots):
//     P1:8(guards s2@-4,s3@-5 m=5) P2:2(s7@P1 m=2) P3:2(s4@P2 m=2)
//     P4:4(s4 m=3) P5:8(s7 m=5..wait s6@P8- m=... verified in text) P6:2
//     (s3@P5 m=2) P7:2(s1@P6 m=2) P8:4(s1 m=3)
//   Stage k-counters advance +64 per stage of that class (2/class/iter),
//   wrap mod K (last-iter restage of t0/t1 is harmless; last-iter P7/P8
//   reads are dead but defined).
//   LDS swizzle (0 conflicts, verified): row r stores logical 16B-granule g
//   at phys granule g^(r&7); staging pre-swizzles the GLOBAL source column
//   (g=(lane&7)^(lane>>3)) so global_load_lds dests stay lane-contiguous.
//   XCD swizzle REMOVED (R2: FETCH 302->553MB regression, no dur change).
// ============================================================================

#define BM 256
#define BN 256
#define BK 64
#define NTHREADS 512

typedef __bf16 bf16x8 __attribute__((ext_vector_type(8)));
typedef float floatx4 __attribute__((ext_vector_type(4)));

// round-to-nearest-even f32 -> bf16 bits
__device__ inline unsigned short f2bf(float f) {
    union { float f; unsigned int u; } v; v.f = f;
    unsigned int u = v.u;
    return (unsigned short)((u + 0x7fffu + ((u >> 16) & 1u)) >> 16);
}

// One launch converts both x and w (saves a launch + tail).
__global__ void cvt_both_f32_to_bf16(const float* __restrict__ x,
                                     const float* __restrict__ w,
                                     unsigned short* __restrict__ xb,
                                     unsigned short* __restrict__ wb,
                                     int nx4, int nw4) {
    int i = blockIdx.x * blockDim.x + threadIdx.x;
    int stride = gridDim.x * blockDim.x;
    int ntot = nx4 + nw4;
    for (int idx = i; idx < ntot; idx += stride) {
        const float4* src; ushort4* dst; int j;
        if (idx < nx4) { src = (const float4*)x; dst = (ushort4*)xb; j = idx; }
        else           { src = (const float4*)w; dst = (ushort4*)wb; j = idx - nx4; }
        float4 f = src[j];
        ushort4 o;
        o.x = f2bf(f.x); o.y = f2bf(f.y); o.z = f2bf(f.z); o.w = f2bf(f.w);
        dst[j] = o;
    }
}

#define GLD16(SRC, DST) __builtin_amdgcn_global_load_lds( \
    (const __attribute__((address_space(1))) void*)(SRC),  \
    (__attribute__((address_space(3))) void*)(DST), 16, 0, 0)

#define BARRIER() __builtin_amdgcn_s_barrier()
#define WAITVM(N) asm volatile("s_waitcnt vmcnt(" #N ")")

__global__ __launch_bounds__(NTHREADS, 2)
void gemm_bt_bias_8ph(const unsigned short* __restrict__ A,
                      const unsigned short* __restrict__ B,
                      const float* __restrict__ bias,
                      float* __restrict__ C,
                      int M, int N, int K) {
    extern __shared__ unsigned short lds[];   // 8 slots x 8192 elem = 128 KiB

    const int tid  = threadIdx.x;
    const int lane = tid & 63;
    const int wave = tid >> 6;          // 0..7
    const int wrow = wave >> 2;         // 0..1 : M half -> A slot
    const int wcol = wave & 3;          // 0..3 : N quarter -> B slot + range

    const int bm = blockIdx.y * BM;
    const int bn = blockIdx.x * BN;

    // ---- staging addressing (pre-swizzled global source) ----
    const int g  = (lane & 7) ^ (lane >> 3);    // logical 16B granule
    const int rs = lane >> 3;                   // row within 8-row chunk
    const int c0 = wave * 2;                    // this wave's chunks c0,c0+1
    const int r0 = c0 * 8 + rs;                 // rows within a 128-row half
    const int r1 = r0 + 8;

    const unsigned short* gBlo0 = B + (size_t)(bn + r0) * K + g * 8;
    const unsigned short* gBlo1 = B + (size_t)(bn + r1) * K + g * 8;
    const unsigned short* gBhi0 = gBlo0 + (size_t)128 * K;
    const unsigned short* gBhi1 = gBlo1 + (size_t)128 * K;
    const unsigned short* gAlo0 = A + (size_t)(bm + r0) * K + g * 8;
    const unsigned short* gAlo1 = A + (size_t)(bm + r1) * K + g * 8;
    const unsigned short* gAhi0 = gAlo0 + (size_t)128 * K;
    const unsigned short* gAhi1 = gAlo1 + (size_t)128 * K;

    unsigned short* const d0 = lds + c0 * 512;  // wave-uniform chunk bases
    unsigned short* const d1 = d0 + 512;

    int kBlo = 0, kBhi = 0, kAlo = 0, kAhi = 0;   // uniform -> SGPR

#define STAGE(P0, P1X, KV, SLOT) do {             \
        GLD16((P0) + KV, d0 + (SLOT) * 8192);     \
        GLD16((P1X) + KV, d1 + (SLOT) * 8192);    \
        KV += BK; if (KV >= K) KV -= K; } while (0)

    // ---- fragment addressing ----
    const int lr = lane & 15;
    const int lq = lane >> 4;
    const int sw = lr & 7;
    const unsigned short* const aslot0 = lds + (2 + wrow) * 8192;
    const unsigned short* const bslot0 = lds + (wcol >> 1) * 8192;
    const unsigned short* const aslot1 = aslot0 + 4 * 8192;
    const unsigned short* const bslot1 = bslot0 + 4 * 8192;
    const int bro = (wcol & 1) * 64;

    floatx4 acc[8][4];
#pragma unroll
    for (int mi = 0; mi < 8; ++mi)
#pragma unroll
        for (int ni = 0; ni < 4; ++ni)
            acc[mi][ni] = (floatx4){0.f, 0.f, 0.f, 0.f};

    bf16x8 afA[4][2];   // A frags, m-half 0 of current tile (static idx only)
    bf16x8 afB[4][2];   // A frags, m-half 1
    bf16x8 b01[2][2];   // B frags ni=0,1
    bf16x8 b23[2][2];   // B frags ni=2,3

#define LDA(DST, BASE, MH) do {                                                \
    _Pragma("unroll")                                                          \
    for (int mi = 0; mi < 4; ++mi) {                                           \
        _Pragma("unroll")                                                      \
        for (int ks = 0; ks < 2; ++ks)                                         \
            DST[mi][ks] = *(const bf16x8*)((BASE) +                            \
                ((MH) * 64 + mi * 16 + lr) * 64 + (((ks << 2) | lq) ^ sw) * 8);\
    } } while (0)

#define LDB(DST, BASE, NB) do {                                                \
    _Pragma("unroll")                                                          \
    for (int ni = 0; ni < 2; ++ni) {                                           \
        _Pragma("unroll")                                                      \
        for (int ks = 0; ks < 2; ++ks)                                         \
            DST[ni][ks] = *(const bf16x8*)((BASE) +                            \
                (bro + ((NB) + ni) * 16 + lr) * 64 + (((ks << 2) | lq) ^ sw) * 8);\
    } } while (0)

#define MFMAQ(MH, AF, NH, BF) do {                                             \
    __builtin_amdgcn_s_setprio(1);                                             \
    _Pragma("unroll")                                                          \
    for (int mi = 0; mi < 4; ++mi) {                                           \
        _Pragma("unroll")                                                      \
        for (int ni = 0; ni < 2; ++ni) {                                       \
            _Pragma("unroll")                                                  \
            for (int ks = 0; ks < 2; ++ks)                                     \
                acc[(MH) * 4 + mi][(NH) * 2 + ni] =                            \
                    __builtin_amdgcn_mfma_f32_16x16x32_bf16(                   \
                        AF[mi][ks], BF[ni][ks],                                \
                        acc[(MH) * 4 + mi][(NH) * 2 + ni], 0, 0, 0);           \
        } }                                                                    \
    __builtin_amdgcn_s_setprio(0); } while (0)

    // ---- prologue (mimics P3..P8 of iteration -1) ----
    STAGE(gBlo0, gBlo1, kBlo, 0);   // B.lo t0  (k=0)
    STAGE(gBhi0, gBhi1, kBhi, 1);   // B.hi t0
    STAGE(gAlo0, gAlo1, kAlo, 2);   // A.lo t0
    STAGE(gAhi0, gAhi1, kAhi, 3);   // A.hi t0
    STAGE(gBhi0, gBhi1, kBhi, 5);   // B.hi t1  (k=64)
    STAGE(gAlo0, gAlo1, kAlo, 6);   // A.lo t1
    WAITVM(4);                      // s0..s3 landed (s5,s6 may fly)
    BARRIER();                      // cross-wave: everyone's t0 landed
    LDA(afA, aslot0, 0);            // P7-equiv read
    LDB(b01, bslot0, 0);            // P8-equiv read

    const int nIter = K >> 7;   // K/128: 2 K-tiles (BK=64) per iteration
    for (int it = 0; it < nIter; ++it) {
        // P1: reads bfr23(2I); stage A.hi(2I+1)->s7; MFMA Q(0,0)
        LDB(b23, bslot0, 2);
        STAGE(gAhi0, gAhi1, kAhi, 7);
        BARRIER();
        MFMAQ(0, afA, 0, b01);
        WAITVM(8);                  // guards P2 reads (s2/s3, m=5)
        BARRIER();
        // P2: reads afB(2I); stage B.lo(2I+1)->s4; MFMA Q(0,1)
        LDA(afB, aslot0, 1);
        STAGE(gBlo0, gBlo1, kBlo, 4);
        BARRIER();
        MFMAQ(0, afA, 1, b23);
        WAITVM(2);                  // guards P3 reads (s7@P1, m=2)
        BARRIER();
        // P3: reads afA(2I+1); stage B.lo(2I+2)->s0; MFMA Q(1,0)
        LDA(afA, aslot1, 0);
        STAGE(gBlo0, gBlo1, kBlo, 0);
        BARRIER();
        MFMAQ(1, afB, 0, b01);
        WAITVM(2);                  // guards P4 reads (s4@P2, m=2)
        BARRIER();
        // P4: reads bfr01(2I+1); stage A.lo(2I+2)->s2; MFMA Q(1,1)
        LDB(b01, bslot1, 0);
        STAGE(gAlo0, gAlo1, kAlo, 2);
        BARRIER();
        MFMAQ(1, afB, 1, b23);
        WAITVM(4);                  // guards P5 reads (s4, m=3)
        BARRIER();
        // P5: reads bfr23(2I+1); stage A.hi(2I+2)->s3; MFMA Q(0,0)
        LDB(b23, bslot1, 2);
        STAGE(gAhi0, gAhi1, kAhi, 3);
        BARRIER();
        MFMAQ(0, afA, 0, b01);
        WAITVM(8);                  // guards P6 reads (s6/s7, m=5)
        BARRIER();
        // P6: reads afB(2I+1); stage B.hi(2I+2)->s1; MFMA Q(0,1)
        LDA(afB, aslot1, 1);
        STAGE(gBhi0, gBhi1, kBhi, 1);
        BARRIER();
        MFMAQ(0, afA, 1, b23);
        WAITVM(2);                  // guards P7 reads (s3@P5, m=2)
        BARRIER();
        // P7: reads afA(2I+2); stage B.hi(2I+3)->s5; MFMA Q(1,0)
        LDA(afA, aslot0, 0);
        STAGE(gBhi0, gBhi1, kBhi, 5);
        BARRIER();
        MFMAQ(1, afB, 0, b01);
        WAITVM(2);                  // guards P8 reads (s1@P6, m=2)
        BARRIER();
        // P8: reads bfr01(2I+2); stage A.lo(2I+3)->s6; MFMA Q(1,1)
        LDB(b01, bslot0, 0);
        STAGE(gAlo0, gAlo1, kAlo, 6);
        BARRIER();
        MFMAQ(1, afB, 1, b23);
        WAITVM(4);                  // guards P1' reads (s1@P6, m=3)
        BARRIER();
    }
    asm volatile("s_waitcnt vmcnt(0)");     // drain DMA before LDS teardown

    // ---- epilogue: C/D layout col=lane&15, row=lq*4+r (verified) ----
    const int wm = wrow * 128;
    const int wn = wcol * 64;
#pragma unroll
    for (int ni = 0; ni < 4; ++ni) {
        int n = bn + wn + ni * 16 + lr;
        float bv = bias[n];
#pragma unroll
        for (int mi = 0; mi < 8; ++mi) {
            int m0 = bm + wm + mi * 16 + lq * 4;
#pragma unroll
            for (int r = 0; r < 4; ++r)
                C[(size_t)(m0 + r) * N + n] = acc[mi][ni][r] + bv;
        }
    }
#undef STAGE
#undef LDA
#undef LDB
#undef MFMAQ
}

extern "C" void kernel_launch(void* const* d_in, const int* in_sizes, int n_in,
                              void* d_out, int out_size, void* d_ws, size_t ws_size,
                              hipStream_t stream) {
    const float* x    = (const float*)d_in[0];  // [M,K]
    const float* w    = (const float*)d_in[1];  // [N,K]
    const float* bias = (const float*)d_in[2];  // [N]
    float* out = (float*)d_out;

    const int N = in_sizes[2];             // 4096
    const int K = in_sizes[1] / N;         // 4096
    const int M = in_sizes[0] / K;         // 8192

    unsigned short* xb = (unsigned short*)d_ws;              // [M,K] bf16
    unsigned short* wb = xb + (size_t)M * K;                 // [N,K] bf16

    cvt_both_f32_to_bf16<<<4096, 256, 0, stream>>>(x, w, xb, wb,
                                                   (M * K) / 4, (N * K) / 4);

    static bool attr_set = false;
    if (!attr_set) {
        (void)hipFuncSetAttribute((const void*)gemm_bt_bias_8ph,
                                  hipFuncAttributeMaxDynamicSharedMemorySize,
                                  131072);
        attr_set = true;
    }

    dim3 grid(N / BN, M / BM);   // (16, 32) = 512 blocks
    gemm_bt_bias_8ph<<<grid, NTHREADS, 131072, stream>>>(xb, wb, bias, out, M, N, K);
}